// Round 3
// baseline (719.267 us; speedup 1.0000x reference)
//
#include <hip/hip_runtime.h>
#include <stdint.h>

#define N_NODES 50000
#define M_EDGES 25000
#define NNZF    800000
#define F_IN    128
#define HID     256
#define F_OUT   128

// ---------------- histogram (int counts) ----------------
__global__ void hist_deg(const int* __restrict__ nidx, const int* __restrict__ eidx,
                         int* __restrict__ cntN, int* __restrict__ cntE, int nnz) {
    int i = blockIdx.x * blockDim.x + threadIdx.x;
    if (i < nnz) {
        atomicAdd(cntN + nidx[i], 1);
        atomicAdd(cntE + eidx[i], 1);
    }
}

// ---------------- fused: exclusive scan + cursor init + inverse degree ----------------
// block 0 handles the node arrays, block 1 the edge arrays.
__global__ __launch_bounds__(256) void scan_two(
    const int* __restrict__ cntN, int* __restrict__ startN, int* __restrict__ curN,
    float* __restrict__ invN, int nN,
    const int* __restrict__ cntE, int* __restrict__ startE, int* __restrict__ curE,
    float* __restrict__ invE, int nE) {
    const int* cnt; int* starts; int* cur; float* inv; int n;
    if (blockIdx.x == 0) { cnt = cntN; starts = startN; cur = curN; inv = invN; n = nN; }
    else                 { cnt = cntE; starts = startE; cur = curE; inv = invE; n = nE; }

    __shared__ int part[256];
    __shared__ int partx[256];
    int tid = threadIdx.x;
    int chunk = (n + 255) / 256;
    int lo = tid * chunk;
    int hi = lo + chunk; if (hi > n) hi = n;
    int s = 0;
    for (int i = lo; i < hi; ++i) s += cnt[i];
    part[tid] = s;
    __syncthreads();
    if (tid == 0) {
        int run = 0;
        for (int i = 0; i < 256; ++i) { partx[i] = run; run += part[i]; }
    }
    __syncthreads();
    int run = partx[tid];
    for (int i = lo; i < hi; ++i) {
        int c = cnt[i];
        starts[i] = run;
        cur[i] = run;
        inv[i] = (c > 0) ? 1.0f / (float)c : 0.0f;
        run += c;
    }
    if (hi == n && lo < n) starts[n] = run;
}

// ---------------- CSR fill (cursors pre-initialized to starts) ----------------
__global__ void fill_csr(const int* __restrict__ nidx, const int* __restrict__ eidx,
                         int* __restrict__ curN, int* __restrict__ curE,
                         int* __restrict__ listN, int* __restrict__ listE, int nnz) {
    int i = blockIdx.x * blockDim.x + threadIdx.x;
    if (i < nnz) {
        int nd = nidx[i], ed = eidx[i];
        int pe = atomicAdd(curE + ed, 1);
        listE[pe] = nd;                       // sources (nodes) grouped by edge
        int pn = atomicAdd(curN + nd, 1);
        listN[pn] = ed;                       // sources (edges) grouped by node
    }
}

// ---------------- gather segment-sum of 128-wide rows ----------------
// one wave (64 lanes) per destination row; lane handles float2; 4 independent accumulators
template<bool SCALE_DST, bool ADD_BIAS>
__global__ __launch_bounds__(256) void gather_rows(
    const float* __restrict__ src, const int* __restrict__ starts,
    const int* __restrict__ list, const float* __restrict__ dstscale,
    const float* __restrict__ bias, float* __restrict__ dst, int rows) {
    int row = blockIdx.x * 4 + (threadIdx.x >> 6);
    if (row >= rows) return;
    int lane = threadIdx.x & 63;
    const float* sp = src + lane * 2;
    int s0 = starts[row], s1 = starts[row + 1];
    float a0x = 0.f, a0y = 0.f, a1x = 0.f, a1y = 0.f;
    float a2x = 0.f, a2y = 0.f, a3x = 0.f, a3y = 0.f;
    int j = s0;
    for (; j + 4 <= s1; j += 4) {
        int i0 = list[j + 0], i1 = list[j + 1], i2 = list[j + 2], i3 = list[j + 3];
        float2 v0 = *reinterpret_cast<const float2*>(sp + (int64_t)i0 * 128);
        float2 v1 = *reinterpret_cast<const float2*>(sp + (int64_t)i1 * 128);
        float2 v2 = *reinterpret_cast<const float2*>(sp + (int64_t)i2 * 128);
        float2 v3 = *reinterpret_cast<const float2*>(sp + (int64_t)i3 * 128);
        a0x += v0.x; a0y += v0.y;
        a1x += v1.x; a1y += v1.y;
        a2x += v2.x; a2y += v2.y;
        a3x += v3.x; a3y += v3.y;
    }
    for (; j < s1; ++j) {
        int i0 = list[j];
        float2 v0 = *reinterpret_cast<const float2*>(sp + (int64_t)i0 * 128);
        a0x += v0.x; a0y += v0.y;
    }
    float ax = (a0x + a1x) + (a2x + a3x);
    float ay = (a0y + a1y) + (a2y + a3y);
    if (SCALE_DST) { float sc = dstscale[row]; ax *= sc; ay *= sc; }
    if (ADD_BIAS)  { ax += bias[lane * 2]; ay += bias[lane * 2 + 1]; }
    float2 o; o.x = ax; o.y = ay;
    *reinterpret_cast<float2*>(dst + (int64_t)row * 128 + lane * 2) = o;
}

// ---------------- tiled fp32 GEMM ----------------
template<bool SCALE_A, bool ELU, bool HAS_BIAS>
__global__ __launch_bounds__(256) void gemm_tiled(
    const float* __restrict__ A, const float* __restrict__ B,
    const float* __restrict__ bias, const float* __restrict__ rowscale,
    float* __restrict__ C, int Mr, int K, int Nc) {
    __shared__ float As[64][17];
    __shared__ float Bs[16][65];
    int tid = threadIdx.x;
    int tx = tid & 15, ty = tid >> 4;
    int rowBase = blockIdx.x * 64;
    int colBase = blockIdx.y * 64;

    int lr = tid >> 2, lc = (tid & 3) << 2;
    int br = tid >> 4, bc = (tid & 15) << 2;

    float c[4][4] = {};

    for (int k0 = 0; k0 < K; k0 += 16) {
        int ar = rowBase + lr;
        float4 av = make_float4(0.f, 0.f, 0.f, 0.f);
        if (ar < Mr) {
            av = *reinterpret_cast<const float4*>(A + (int64_t)ar * K + k0 + lc);
            if (SCALE_A) {
                float sc = rowscale[ar];
                av.x *= sc; av.y *= sc; av.z *= sc; av.w *= sc;
            }
        }
        As[lr][lc + 0] = av.x; As[lr][lc + 1] = av.y;
        As[lr][lc + 2] = av.z; As[lr][lc + 3] = av.w;

        float4 bv = *reinterpret_cast<const float4*>(B + (int64_t)(k0 + br) * Nc + colBase + bc);
        Bs[br][bc + 0] = bv.x; Bs[br][bc + 1] = bv.y;
        Bs[br][bc + 2] = bv.z; Bs[br][bc + 3] = bv.w;

        __syncthreads();
        #pragma unroll
        for (int kk = 0; kk < 16; ++kk) {
            float a0 = As[ty * 4 + 0][kk];
            float a1 = As[ty * 4 + 1][kk];
            float a2 = As[ty * 4 + 2][kk];
            float a3 = As[ty * 4 + 3][kk];
            float b0 = Bs[kk][tx * 4 + 0];
            float b1v = Bs[kk][tx * 4 + 1];
            float b2v = Bs[kk][tx * 4 + 2];
            float b3v = Bs[kk][tx * 4 + 3];
            c[0][0] += a0 * b0;  c[0][1] += a0 * b1v;  c[0][2] += a0 * b2v;  c[0][3] += a0 * b3v;
            c[1][0] += a1 * b0;  c[1][1] += a1 * b1v;  c[1][2] += a1 * b2v;  c[1][3] += a1 * b3v;
            c[2][0] += a2 * b0;  c[2][1] += a2 * b1v;  c[2][2] += a2 * b2v;  c[2][3] += a2 * b3v;
            c[3][0] += a3 * b0;  c[3][1] += a3 * b1v;  c[3][2] += a3 * b2v;  c[3][3] += a3 * b3v;
        }
        __syncthreads();
    }

    #pragma unroll
    for (int i = 0; i < 4; ++i) {
        int r = rowBase + ty * 4 + i;
        if (r >= Mr) continue;
        #pragma unroll
        for (int j = 0; j < 4; ++j) {
            int col = colBase + tx * 4 + j;
            float v = c[i][j];
            if (HAS_BIAS) v += bias[col];
            if (ELU) v = (v > 0.f) ? v : expm1f(v);
            C[(int64_t)r * Nc + col] = v;
        }
    }
}

// ---------------- launch ----------------
extern "C" void kernel_launch(void* const* d_in, const int* in_sizes, int n_in,
                              void* d_out, int out_size, void* d_ws, size_t ws_size,
                              hipStream_t stream) {
    const float* x   = (const float*)d_in[0];
    const float* W1  = (const float*)d_in[1];
    const float* b1  = (const float*)d_in[2];
    const float* W2  = (const float*)d_in[3];
    const float* b2  = (const float*)d_in[4];
    const int*   nidx = (const int*)d_in[5];
    const int*   eidx = (const int*)d_in[6];

    float* out   = (float*)d_out;                      // [N, 128]
    float* e_out = out + (size_t)N_NODES * F_OUT;      // [M, 128]

    char* ws = (char*)d_ws;
    size_t off = 0;
    auto alloc = [&](size_t bytes) -> void* {
        void* p = ws + off;
        off += (bytes + 511) & ~(size_t)511;
        return p;
    };
    int* cntN    = (int*)alloc((size_t)(N_NODES + M_EDGES) * 4);   // contiguous: cntN | cntE
    int* cntE    = cntN + N_NODES;
    float* Dinv  = (float*)alloc((size_t)N_NODES * 4);
    float* Binv  = (float*)alloc((size_t)M_EDGES * 4);
    int* startN  = (int*)alloc((size_t)(N_NODES + 1) * 4);
    int* startE  = (int*)alloc((size_t)(M_EDGES + 1) * 4);
    int* curN    = (int*)alloc((size_t)N_NODES * 4);
    int* curE    = (int*)alloc((size_t)M_EDGES * 4);
    int* listN   = (int*)alloc((size_t)NNZF * 4);      // edges grouped by node
    int* listE   = (int*)alloc((size_t)NNZF * 4);      // nodes grouped by edge
    float* y     = (float*)alloc((size_t)M_EDGES * F_IN * 4);   // [M,128]
    float* z     = (float*)alloc((size_t)N_NODES * F_IN * 4);   // [N,128]; reused for hp
    float* h     = (float*)alloc((size_t)N_NODES * HID * 4);    // [N,256]

    // only the counters need zeroing; every other buffer is fully overwritten
    hipMemsetAsync(cntN, 0, (size_t)(N_NODES + M_EDGES) * 4, stream);

    hist_deg<<<(NNZF + 255) / 256, 256, 0, stream>>>(nidx, eidx, cntN, cntE, NNZF);
    scan_two<<<2, 256, 0, stream>>>(cntN, startN, curN, Dinv, N_NODES,
                                    cntE, startE, curE, Binv, M_EDGES);
    fill_csr<<<(NNZF + 255) / 256, 256, 0, stream>>>(nidx, eidx, curN, curE,
                                                     listN, listE, NNZF);

    // layer 1 propagation (feature width 128, pre-GEMM)
    gather_rows<true, false><<<(M_EDGES + 3) / 4, 256, 0, stream>>>(
        x, startE, listE, Binv, nullptr, y, M_EDGES);          // y = Binv .* (S^T x)
    gather_rows<false, false><<<(N_NODES + 3) / 4, 256, 0, stream>>>(
        y, startN, listN, nullptr, nullptr, z, N_NODES);       // z = S y

    // h = elu( (Dinv .* z) @ W1 + b1 )   [N,256]
    dim3 g1((N_NODES + 63) / 64, HID / 64);
    gemm_tiled<true, true, true><<<g1, 256, 0, stream>>>(z, W1, b1, Dinv, h, N_NODES, F_IN, HID);

    // hp = h @ W2  [N,128]  (into z)
    dim3 g2((N_NODES + 63) / 64, F_OUT / 64);
    gemm_tiled<false, false, false><<<g2, 256, 0, stream>>>(h, W2, nullptr, nullptr, z, N_NODES, HID, F_OUT);

    // e = Binv .* (S^T hp)  -> output slot
    gather_rows<true, false><<<(M_EDGES + 3) / 4, 256, 0, stream>>>(
        z, startE, listE, Binv, nullptr, e_out, M_EDGES);
    // out = Dinv .* (S e) + b2
    gather_rows<true, true><<<(N_NODES + 3) / 4, 256, 0, stream>>>(
        e_out, startN, listN, Dinv, b2, out, N_NODES);
}

// Round 4
// 560.029 us; speedup vs baseline: 1.2843x; 1.2843x over previous
//
#include <hip/hip_runtime.h>
#include <stdint.h>

#define N_NODES 50000
#define M_EDGES 25000
#define NNZF    800000
#define F_IN    128
#define HID     256
#define F_OUT   128

#define NB_N 49   // ceil(50000/1024)
#define NB_E 25   // ceil(25000/1024)
#define NTILES (NB_N + NB_E)

// ---------------- histogram (int counts), int4 index loads ----------------
__global__ void hist_deg(const int* __restrict__ nidx, const int* __restrict__ eidx,
                         int* __restrict__ cntN, int* __restrict__ cntE, int nnz) {
    int i = (blockIdx.x * blockDim.x + threadIdx.x) * 4;
    if (i + 3 < nnz) {
        int4 a = *reinterpret_cast<const int4*>(nidx + i);
        int4 b = *reinterpret_cast<const int4*>(eidx + i);
        atomicAdd(cntN + a.x, 1); atomicAdd(cntN + a.y, 1);
        atomicAdd(cntN + a.z, 1); atomicAdd(cntN + a.w, 1);
        atomicAdd(cntE + b.x, 1); atomicAdd(cntE + b.y, 1);
        atomicAdd(cntE + b.z, 1); atomicAdd(cntE + b.w, 1);
    } else {
        for (; i < nnz; ++i) {
            atomicAdd(cntN + nidx[i], 1);
            atomicAdd(cntE + eidx[i], 1);
        }
    }
}

// ---------------- hierarchical scan, phase A: per-1024-tile sums ----------------
__global__ __launch_bounds__(256) void scan_sums(const int* __restrict__ cnt,
                                                 int* __restrict__ bsums) {
    int b = blockIdx.x;
    int tile, n; const int* base;
    if (b < NB_N) { base = cnt;           n = N_NODES; tile = b; }
    else          { base = cnt + N_NODES; n = M_EDGES; tile = b - NB_N; }
    int i0 = tile * 1024 + threadIdx.x * 4;
    int s = 0;
    if (i0 < n) {                     // n % 4 == 0 so int4 never straddles
        int4 v = *reinterpret_cast<const int4*>(base + i0);
        s = v.x + v.y + v.z + v.w;
    }
    for (int off = 32; off > 0; off >>= 1) s += __shfl_down(s, off, 64);
    __shared__ int ws[4];
    int wid = threadIdx.x >> 6, lane = threadIdx.x & 63;
    if (lane == 0) ws[wid] = s;
    __syncthreads();
    if (threadIdx.x == 0) bsums[b] = ws[0] + ws[1] + ws[2] + ws[3];
}

// ---------------- phase B: per-tile scan + write starts/cur/inv (coalesced) ----------------
__global__ __launch_bounds__(256) void scan_write(
    const int* __restrict__ cnt, const int* __restrict__ bsums,
    int* __restrict__ startN, int* __restrict__ curN, float* __restrict__ invN,
    int* __restrict__ startE, int* __restrict__ curE, float* __restrict__ invE) {
    int b = blockIdx.x;
    int tile, n, lo; const int* base; int* starts; int* cur; float* inv;
    if (b < NB_N) { base = cnt;           n = N_NODES; tile = b;        starts = startN; cur = curN; inv = invN; lo = 0; }
    else          { base = cnt + N_NODES; n = M_EDGES; tile = b - NB_N; starts = startE; cur = curE; inv = invE; lo = NB_N; }
    int tid = threadIdx.x;
    int wid = tid >> 6, lane = tid & 63;

    // block offset = sum of this region's preceding tile sums
    __shared__ int red[4];
    int partial = 0;
    for (int i = lo + tid; i < b; i += 256) partial += bsums[i];
    for (int off = 32; off > 0; off >>= 1) partial += __shfl_down(partial, off, 64);
    if (lane == 0) red[wid] = partial;
    __syncthreads();
    int blockoff = red[0] + red[1] + red[2] + red[3];

    int i0 = tile * 1024 + tid * 4;
    int4 v = make_int4(0, 0, 0, 0);
    if (i0 < n) v = *reinterpret_cast<const int4*>(base + i0);
    int tsum = v.x + v.y + v.z + v.w;

    // wave inclusive scan of thread sums
    int x = tsum;
    for (int d = 1; d < 64; d <<= 1) {
        int y = __shfl_up(x, d, 64);
        if (lane >= d) x += y;
    }
    int wexcl = x - tsum;
    __shared__ int wsum[4];
    if (lane == 63) wsum[wid] = x;
    __syncthreads();
    int woff = 0;
    for (int w = 0; w < wid; ++w) woff += wsum[w];
    int excl = blockoff + woff + wexcl;

    if (i0 < n) {
        int4 st;
        st.x = excl;
        st.y = st.x + v.x;
        st.z = st.y + v.y;
        st.w = st.z + v.z;
        *reinterpret_cast<int4*>(starts + i0) = st;
        *reinterpret_cast<int4*>(cur + i0) = st;
        float4 iv;
        iv.x = (v.x > 0) ? 1.0f / (float)v.x : 0.0f;
        iv.y = (v.y > 0) ? 1.0f / (float)v.y : 0.0f;
        iv.z = (v.z > 0) ? 1.0f / (float)v.z : 0.0f;
        iv.w = (v.w > 0) ? 1.0f / (float)v.w : 0.0f;
        *reinterpret_cast<float4*>(inv + i0) = iv;
    }
    if (b == 0 && tid == 0) { startN[N_NODES] = NNZF; startE[M_EDGES] = NNZF; }
}

// ---------------- CSR fill (cursors pre-initialized to starts), int4 index loads ----------------
__global__ void fill_csr(const int* __restrict__ nidx, const int* __restrict__ eidx,
                         int* __restrict__ curN, int* __restrict__ curE,
                         int* __restrict__ listN, int* __restrict__ listE, int nnz) {
    int i = (blockIdx.x * blockDim.x + threadIdx.x) * 4;
    if (i + 3 < nnz) {
        int4 a = *reinterpret_cast<const int4*>(nidx + i);
        int4 b = *reinterpret_cast<const int4*>(eidx + i);
        listE[atomicAdd(curE + b.x, 1)] = a.x;
        listE[atomicAdd(curE + b.y, 1)] = a.y;
        listE[atomicAdd(curE + b.z, 1)] = a.z;
        listE[atomicAdd(curE + b.w, 1)] = a.w;
        listN[atomicAdd(curN + a.x, 1)] = b.x;
        listN[atomicAdd(curN + a.y, 1)] = b.y;
        listN[atomicAdd(curN + a.z, 1)] = b.z;
        listN[atomicAdd(curN + a.w, 1)] = b.w;
    } else {
        for (; i < nnz; ++i) {
            int nd = nidx[i], ed = eidx[i];
            listE[atomicAdd(curE + ed, 1)] = nd;
            listN[atomicAdd(curN + nd, 1)] = ed;
        }
    }
}

// ---------------- gather segment-sum of 128-wide rows ----------------
template<bool SCALE_DST, bool ADD_BIAS>
__global__ __launch_bounds__(256) void gather_rows(
    const float* __restrict__ src, const int* __restrict__ starts,
    const int* __restrict__ list, const float* __restrict__ dstscale,
    const float* __restrict__ bias, float* __restrict__ dst, int rows) {
    int row = blockIdx.x * 4 + (threadIdx.x >> 6);
    if (row >= rows) return;
    int lane = threadIdx.x & 63;
    const float* sp = src + lane * 2;
    int s0 = starts[row], s1 = starts[row + 1];
    float a0x = 0.f, a0y = 0.f, a1x = 0.f, a1y = 0.f;
    float a2x = 0.f, a2y = 0.f, a3x = 0.f, a3y = 0.f;
    int j = s0;
    for (; j + 4 <= s1; j += 4) {
        int i0 = list[j + 0], i1 = list[j + 1], i2 = list[j + 2], i3 = list[j + 3];
        float2 v0 = *reinterpret_cast<const float2*>(sp + (int64_t)i0 * 128);
        float2 v1 = *reinterpret_cast<const float2*>(sp + (int64_t)i1 * 128);
        float2 v2 = *reinterpret_cast<const float2*>(sp + (int64_t)i2 * 128);
        float2 v3 = *reinterpret_cast<const float2*>(sp + (int64_t)i3 * 128);
        a0x += v0.x; a0y += v0.y;
        a1x += v1.x; a1y += v1.y;
        a2x += v2.x; a2y += v2.y;
        a3x += v3.x; a3y += v3.y;
    }
    for (; j < s1; ++j) {
        int i0 = list[j];
        float2 v0 = *reinterpret_cast<const float2*>(sp + (int64_t)i0 * 128);
        a0x += v0.x; a0y += v0.y;
    }
    float ax = (a0x + a1x) + (a2x + a3x);
    float ay = (a0y + a1y) + (a2y + a3y);
    if (SCALE_DST) { float sc = dstscale[row]; ax *= sc; ay *= sc; }
    if (ADD_BIAS)  { ax += bias[lane * 2]; ay += bias[lane * 2 + 1]; }
    float2 o; o.x = ax; o.y = ay;
    *reinterpret_cast<float2*>(dst + (int64_t)row * 128 + lane * 2) = o;
}

// ---------------- tiled fp32 GEMM ----------------
template<bool SCALE_A, bool ELU, bool HAS_BIAS>
__global__ __launch_bounds__(256) void gemm_tiled(
    const float* __restrict__ A, const float* __restrict__ B,
    const float* __restrict__ bias, const float* __restrict__ rowscale,
    float* __restrict__ C, int Mr, int K, int Nc) {
    __shared__ float As[64][17];
    __shared__ float Bs[16][65];
    int tid = threadIdx.x;
    int tx = tid & 15, ty = tid >> 4;
    int rowBase = blockIdx.x * 64;
    int colBase = blockIdx.y * 64;

    int lr = tid >> 2, lc = (tid & 3) << 2;
    int br = tid >> 4, bc = (tid & 15) << 2;

    float c[4][4] = {};

    for (int k0 = 0; k0 < K; k0 += 16) {
        int ar = rowBase + lr;
        float4 av = make_float4(0.f, 0.f, 0.f, 0.f);
        if (ar < Mr) {
            av = *reinterpret_cast<const float4*>(A + (int64_t)ar * K + k0 + lc);
            if (SCALE_A) {
                float sc = rowscale[ar];
                av.x *= sc; av.y *= sc; av.z *= sc; av.w *= sc;
            }
        }
        As[lr][lc + 0] = av.x; As[lr][lc + 1] = av.y;
        As[lr][lc + 2] = av.z; As[lr][lc + 3] = av.w;

        float4 bv = *reinterpret_cast<const float4*>(B + (int64_t)(k0 + br) * Nc + colBase + bc);
        Bs[br][bc + 0] = bv.x; Bs[br][bc + 1] = bv.y;
        Bs[br][bc + 2] = bv.z; Bs[br][bc + 3] = bv.w;

        __syncthreads();
        #pragma unroll
        for (int kk = 0; kk < 16; ++kk) {
            float a0 = As[ty * 4 + 0][kk];
            float a1 = As[ty * 4 + 1][kk];
            float a2 = As[ty * 4 + 2][kk];
            float a3 = As[ty * 4 + 3][kk];
            float b0 = Bs[kk][tx * 4 + 0];
            float b1v = Bs[kk][tx * 4 + 1];
            float b2v = Bs[kk][tx * 4 + 2];
            float b3v = Bs[kk][tx * 4 + 3];
            c[0][0] += a0 * b0;  c[0][1] += a0 * b1v;  c[0][2] += a0 * b2v;  c[0][3] += a0 * b3v;
            c[1][0] += a1 * b0;  c[1][1] += a1 * b1v;  c[1][2] += a1 * b2v;  c[1][3] += a1 * b3v;
            c[2][0] += a2 * b0;  c[2][1] += a2 * b1v;  c[2][2] += a2 * b2v;  c[2][3] += a2 * b3v;
            c[3][0] += a3 * b0;  c[3][1] += a3 * b1v;  c[3][2] += a3 * b2v;  c[3][3] += a3 * b3v;
        }
        __syncthreads();
    }

    #pragma unroll
    for (int i = 0; i < 4; ++i) {
        int r = rowBase + ty * 4 + i;
        if (r >= Mr) continue;
        #pragma unroll
        for (int j = 0; j < 4; ++j) {
            int col = colBase + tx * 4 + j;
            float v = c[i][j];
            if (HAS_BIAS) v += bias[col];
            if (ELU) v = (v > 0.f) ? v : expm1f(v);
            C[(int64_t)r * Nc + col] = v;
        }
    }
}

// ---------------- launch ----------------
extern "C" void kernel_launch(void* const* d_in, const int* in_sizes, int n_in,
                              void* d_out, int out_size, void* d_ws, size_t ws_size,
                              hipStream_t stream) {
    const float* x   = (const float*)d_in[0];
    const float* W1  = (const float*)d_in[1];
    const float* b1  = (const float*)d_in[2];
    const float* W2  = (const float*)d_in[3];
    const float* b2  = (const float*)d_in[4];
    const int*   nidx = (const int*)d_in[5];
    const int*   eidx = (const int*)d_in[6];

    float* out   = (float*)d_out;                      // [N, 128]
    float* e_out = out + (size_t)N_NODES * F_OUT;      // [M, 128]

    char* ws = (char*)d_ws;
    size_t off = 0;
    auto alloc = [&](size_t bytes) -> void* {
        void* p = ws + off;
        off += (bytes + 511) & ~(size_t)511;
        return p;
    };
    int* cntN    = (int*)alloc((size_t)(N_NODES + M_EDGES) * 4);   // contiguous: cntN | cntE
    int* cntE    = cntN + N_NODES;
    float* Dinv  = (float*)alloc((size_t)N_NODES * 4);
    float* Binv  = (float*)alloc((size_t)M_EDGES * 4);
    int* startN  = (int*)alloc((size_t)(N_NODES + 1) * 4);
    int* startE  = (int*)alloc((size_t)(M_EDGES + 1) * 4);
    int* curN    = (int*)alloc((size_t)N_NODES * 4);
    int* curE    = (int*)alloc((size_t)M_EDGES * 4);
    int* bsums   = (int*)alloc((size_t)NTILES * 4);
    int* listN   = (int*)alloc((size_t)NNZF * 4);      // edges grouped by node
    int* listE   = (int*)alloc((size_t)NNZF * 4);      // nodes grouped by edge
    float* y     = (float*)alloc((size_t)M_EDGES * F_IN * 4);   // [M,128]
    float* z     = (float*)alloc((size_t)N_NODES * F_IN * 4);   // [N,128]; reused for hp
    float* h     = (float*)alloc((size_t)N_NODES * HID * 4);    // [N,256]

    // only the counters need zeroing; every other buffer is fully overwritten
    hipMemsetAsync(cntN, 0, (size_t)(N_NODES + M_EDGES) * 4, stream);

    hist_deg<<<(NNZF / 4 + 255) / 256, 256, 0, stream>>>(nidx, eidx, cntN, cntE, NNZF);
    scan_sums<<<NTILES, 256, 0, stream>>>(cntN, bsums);
    scan_write<<<NTILES, 256, 0, stream>>>(cntN, bsums,
                                           startN, curN, Dinv,
                                           startE, curE, Binv);
    fill_csr<<<(NNZF / 4 + 255) / 256, 256, 0, stream>>>(nidx, eidx, curN, curE,
                                                         listN, listE, NNZF);

    // layer 1 propagation (feature width 128, pre-GEMM)
    gather_rows<true, false><<<(M_EDGES + 3) / 4, 256, 0, stream>>>(
        x, startE, listE, Binv, nullptr, y, M_EDGES);          // y = Binv .* (S^T x)
    gather_rows<false, false><<<(N_NODES + 3) / 4, 256, 0, stream>>>(
        y, startN, listN, nullptr, nullptr, z, N_NODES);       // z = S y

    // h = elu( (Dinv .* z) @ W1 + b1 )   [N,256]
    dim3 g1((N_NODES + 63) / 64, HID / 64);
    gemm_tiled<true, true, true><<<g1, 256, 0, stream>>>(z, W1, b1, Dinv, h, N_NODES, F_IN, HID);

    // hp = h @ W2  [N,128]  (into z)
    dim3 g2((N_NODES + 63) / 64, F_OUT / 64);
    gemm_tiled<false, false, false><<<g2, 256, 0, stream>>>(h, W2, nullptr, nullptr, z, N_NODES, HID, F_OUT);

    // e = Binv .* (S^T hp)  -> output slot
    gather_rows<true, false><<<(M_EDGES + 3) / 4, 256, 0, stream>>>(
        z, startE, listE, Binv, nullptr, e_out, M_EDGES);
    // out = Dinv .* (S e) + b2
    gather_rows<true, true><<<(N_NODES + 3) / 4, 256, 0, stream>>>(
        e_out, startN, listN, Dinv, b2, out, N_NODES);
}

// Round 5
// 531.598 us; speedup vs baseline: 1.3530x; 1.0535x over previous
//
#include <hip/hip_runtime.h>
#include <stdint.h>

#define N_NODES 50000
#define M_EDGES 25000
#define NNZF    800000
#define F_IN    128
#define HID     256
#define F_OUT   128

#define NB_N 49   // ceil(50000/1024)
#define NB_E 25   // ceil(25000/1024)
#define NTILES (NB_N + NB_E)

// ---------------- histogram (int counts), 1 entry/thread for max waves ----------------
__global__ void hist_deg(const int* __restrict__ nidx, const int* __restrict__ eidx,
                         int* __restrict__ cntN, int* __restrict__ cntE, int nnz) {
    int i = blockIdx.x * blockDim.x + threadIdx.x;
    if (i < nnz) {
        atomicAdd(cntN + nidx[i], 1);
        atomicAdd(cntE + eidx[i], 1);
    }
}

// ---------------- hierarchical scan, phase A: per-1024-tile sums ----------------
__global__ __launch_bounds__(256) void scan_sums(const int* __restrict__ cnt,
                                                 int* __restrict__ bsums) {
    int b = blockIdx.x;
    int tile, n; const int* base;
    if (b < NB_N) { base = cnt;           n = N_NODES; tile = b; }
    else          { base = cnt + N_NODES; n = M_EDGES; tile = b - NB_N; }
    int i0 = tile * 1024 + threadIdx.x * 4;
    int s = 0;
    if (i0 < n) {                     // n % 4 == 0 so int4 never straddles
        int4 v = *reinterpret_cast<const int4*>(base + i0);
        s = v.x + v.y + v.z + v.w;
    }
    for (int off = 32; off > 0; off >>= 1) s += __shfl_down(s, off, 64);
    __shared__ int ws[4];
    int wid = threadIdx.x >> 6, lane = threadIdx.x & 63;
    if (lane == 0) ws[wid] = s;
    __syncthreads();
    if (threadIdx.x == 0) bsums[b] = ws[0] + ws[1] + ws[2] + ws[3];
}

// ---------------- phase B: per-tile scan + write starts/cur/inv (coalesced) ----------------
__global__ __launch_bounds__(256) void scan_write(
    const int* __restrict__ cnt, const int* __restrict__ bsums,
    int* __restrict__ startN, int* __restrict__ curN, float* __restrict__ invN,
    int* __restrict__ startE, int* __restrict__ curE, float* __restrict__ invE) {
    int b = blockIdx.x;
    int tile, n, lo; const int* base; int* starts; int* cur; float* inv;
    if (b < NB_N) { base = cnt;           n = N_NODES; tile = b;        starts = startN; cur = curN; inv = invN; lo = 0; }
    else          { base = cnt + N_NODES; n = M_EDGES; tile = b - NB_N; starts = startE; cur = curE; inv = invE; lo = NB_N; }
    int tid = threadIdx.x;
    int wid = tid >> 6, lane = tid & 63;

    // block offset = sum of this region's preceding tile sums
    __shared__ int red[4];
    int partial = 0;
    for (int i = lo + tid; i < b; i += 256) partial += bsums[i];
    for (int off = 32; off > 0; off >>= 1) partial += __shfl_down(partial, off, 64);
    if (lane == 0) red[wid] = partial;
    __syncthreads();
    int blockoff = red[0] + red[1] + red[2] + red[3];

    int i0 = tile * 1024 + tid * 4;
    int4 v = make_int4(0, 0, 0, 0);
    if (i0 < n) v = *reinterpret_cast<const int4*>(base + i0);
    int tsum = v.x + v.y + v.z + v.w;

    // wave inclusive scan of thread sums
    int x = tsum;
    for (int d = 1; d < 64; d <<= 1) {
        int y = __shfl_up(x, d, 64);
        if (lane >= d) x += y;
    }
    int wexcl = x - tsum;
    __shared__ int wsum[4];
    if (lane == 63) wsum[wid] = x;
    __syncthreads();
    int woff = 0;
    for (int w = 0; w < wid; ++w) woff += wsum[w];
    int excl = blockoff + woff + wexcl;

    if (i0 < n) {
        int4 st;
        st.x = excl;
        st.y = st.x + v.x;
        st.z = st.y + v.y;
        st.w = st.z + v.z;
        *reinterpret_cast<int4*>(starts + i0) = st;
        *reinterpret_cast<int4*>(cur + i0) = st;
        float4 iv;
        iv.x = (v.x > 0) ? 1.0f / (float)v.x : 0.0f;
        iv.y = (v.y > 0) ? 1.0f / (float)v.y : 0.0f;
        iv.z = (v.z > 0) ? 1.0f / (float)v.z : 0.0f;
        iv.w = (v.w > 0) ? 1.0f / (float)v.w : 0.0f;
        *reinterpret_cast<float4*>(inv + i0) = iv;
    }
    if (b == 0 && tid == 0) { startN[N_NODES] = NNZF; startE[M_EDGES] = NNZF; }
}

// ---------------- CSR fill (cursors pre-initialized to starts), 1 entry/thread ----------------
__global__ void fill_csr(const int* __restrict__ nidx, const int* __restrict__ eidx,
                         int* __restrict__ curN, int* __restrict__ curE,
                         int* __restrict__ listN, int* __restrict__ listE, int nnz) {
    int i = blockIdx.x * blockDim.x + threadIdx.x;
    if (i < nnz) {
        int nd = nidx[i], ed = eidx[i];
        listE[atomicAdd(curE + ed, 1)] = nd;
        listN[atomicAdd(curN + nd, 1)] = ed;
    }
}

// ---------------- gather segment-sum of 128-wide rows ----------------
template<bool SCALE_DST, bool ADD_BIAS>
__global__ __launch_bounds__(256) void gather_rows(
    const float* __restrict__ src, const int* __restrict__ starts,
    const int* __restrict__ list, const float* __restrict__ dstscale,
    const float* __restrict__ bias, float* __restrict__ dst, int rows) {
    int row = blockIdx.x * 4 + (threadIdx.x >> 6);
    if (row >= rows) return;
    int lane = threadIdx.x & 63;
    const float* sp = src + lane * 2;
    int s0 = starts[row], s1 = starts[row + 1];
    float a0x = 0.f, a0y = 0.f, a1x = 0.f, a1y = 0.f;
    float a2x = 0.f, a2y = 0.f, a3x = 0.f, a3y = 0.f;
    int j = s0;
    for (; j + 4 <= s1; j += 4) {
        int i0 = list[j + 0], i1 = list[j + 1], i2 = list[j + 2], i3 = list[j + 3];
        float2 v0 = *reinterpret_cast<const float2*>(sp + (int64_t)i0 * 128);
        float2 v1 = *reinterpret_cast<const float2*>(sp + (int64_t)i1 * 128);
        float2 v2 = *reinterpret_cast<const float2*>(sp + (int64_t)i2 * 128);
        float2 v3 = *reinterpret_cast<const float2*>(sp + (int64_t)i3 * 128);
        a0x += v0.x; a0y += v0.y;
        a1x += v1.x; a1y += v1.y;
        a2x += v2.x; a2y += v2.y;
        a3x += v3.x; a3y += v3.y;
    }
    for (; j < s1; ++j) {
        int i0 = list[j];
        float2 v0 = *reinterpret_cast<const float2*>(sp + (int64_t)i0 * 128);
        a0x += v0.x; a0y += v0.y;
    }
    float ax = (a0x + a1x) + (a2x + a3x);
    float ay = (a0y + a1y) + (a2y + a3y);
    if (SCALE_DST) { float sc = dstscale[row]; ax *= sc; ay *= sc; }
    if (ADD_BIAS)  { ax += bias[lane * 2]; ay += bias[lane * 2 + 1]; }
    float2 o; o.x = ax; o.y = ay;
    *reinterpret_cast<float2*>(dst + (int64_t)row * 128 + lane * 2) = o;
}

// ---------------- tiled fp32 GEMM, k-major A tile + ds_read_b128 fragments ----------------
template<bool SCALE_A, bool ELU, bool HAS_BIAS>
__global__ __launch_bounds__(256) void gemm_tiled(
    const float* __restrict__ A, const float* __restrict__ B,
    const float* __restrict__ bias, const float* __restrict__ rowscale,
    float* __restrict__ C, int Mr, int K, int Nc) {
    __shared__ float Ast[16][68];   // k-major A tile, padded (68*4B = 16B-aligned rows)
    __shared__ float Bs[16][68];
    int tid = threadIdx.x;
    int tx = tid & 15, ty = tid >> 4;
    int rowBase = blockIdx.x * 64;
    int colBase = blockIdx.y * 64;

    int lr = tid >> 2, lc = (tid & 3) << 2;      // A load: row lr, k-offset lc..lc+3
    int br = tid >> 4, bc = (tid & 15) << 2;     // B load: k-row br, col bc..bc+3

    float c[4][4] = {};

    for (int k0 = 0; k0 < K; k0 += 16) {
        int ar = rowBase + lr;
        float4 av = make_float4(0.f, 0.f, 0.f, 0.f);
        if (ar < Mr) {
            av = *reinterpret_cast<const float4*>(A + (int64_t)ar * K + k0 + lc);
            if (SCALE_A) {
                float sc = rowscale[ar];
                av.x *= sc; av.y *= sc; av.z *= sc; av.w *= sc;
            }
        }
        Ast[lc + 0][lr] = av.x;
        Ast[lc + 1][lr] = av.y;
        Ast[lc + 2][lr] = av.z;
        Ast[lc + 3][lr] = av.w;

        float4 bv = *reinterpret_cast<const float4*>(B + (int64_t)(k0 + br) * Nc + colBase + bc);
        *reinterpret_cast<float4*>(&Bs[br][bc]) = bv;

        __syncthreads();
        #pragma unroll
        for (int kk = 0; kk < 16; ++kk) {
            float4 a4 = *reinterpret_cast<const float4*>(&Ast[kk][ty * 4]);
            float4 b4 = *reinterpret_cast<const float4*>(&Bs[kk][tx * 4]);
            c[0][0] += a4.x * b4.x;  c[0][1] += a4.x * b4.y;  c[0][2] += a4.x * b4.z;  c[0][3] += a4.x * b4.w;
            c[1][0] += a4.y * b4.x;  c[1][1] += a4.y * b4.y;  c[1][2] += a4.y * b4.z;  c[1][3] += a4.y * b4.w;
            c[2][0] += a4.z * b4.x;  c[2][1] += a4.z * b4.y;  c[2][2] += a4.z * b4.z;  c[2][3] += a4.z * b4.w;
            c[3][0] += a4.w * b4.x;  c[3][1] += a4.w * b4.y;  c[3][2] += a4.w * b4.z;  c[3][3] += a4.w * b4.w;
        }
        __syncthreads();
    }

    #pragma unroll
    for (int i = 0; i < 4; ++i) {
        int r = rowBase + ty * 4 + i;
        if (r >= Mr) continue;
        float4 o;
        float* cc = c[i];
        o.x = cc[0]; o.y = cc[1]; o.z = cc[2]; o.w = cc[3];
        if (HAS_BIAS) {
            float4 bv = *reinterpret_cast<const float4*>(bias + colBase + tx * 4);
            o.x += bv.x; o.y += bv.y; o.z += bv.z; o.w += bv.w;
        }
        if (ELU) {
            o.x = (o.x > 0.f) ? o.x : expm1f(o.x);
            o.y = (o.y > 0.f) ? o.y : expm1f(o.y);
            o.z = (o.z > 0.f) ? o.z : expm1f(o.z);
            o.w = (o.w > 0.f) ? o.w : expm1f(o.w);
        }
        *reinterpret_cast<float4*>(C + (int64_t)r * Nc + colBase + tx * 4) = o;
    }
}

// ---------------- launch ----------------
extern "C" void kernel_launch(void* const* d_in, const int* in_sizes, int n_in,
                              void* d_out, int out_size, void* d_ws, size_t ws_size,
                              hipStream_t stream) {
    const float* x   = (const float*)d_in[0];
    const float* W1  = (const float*)d_in[1];
    const float* b1  = (const float*)d_in[2];
    const float* W2  = (const float*)d_in[3];
    const float* b2  = (const float*)d_in[4];
    const int*   nidx = (const int*)d_in[5];
    const int*   eidx = (const int*)d_in[6];

    float* out   = (float*)d_out;                      // [N, 128]
    float* e_out = out + (size_t)N_NODES * F_OUT;      // [M, 128]

    char* ws = (char*)d_ws;
    size_t off = 0;
    auto alloc = [&](size_t bytes) -> void* {
        void* p = ws + off;
        off += (bytes + 511) & ~(size_t)511;
        return p;
    };
    int* cntN    = (int*)alloc((size_t)(N_NODES + M_EDGES) * 4);   // contiguous: cntN | cntE
    int* cntE    = cntN + N_NODES;
    float* Dinv  = (float*)alloc((size_t)N_NODES * 4);
    float* Binv  = (float*)alloc((size_t)M_EDGES * 4);
    int* startN  = (int*)alloc((size_t)(N_NODES + 1) * 4);
    int* startE  = (int*)alloc((size_t)(M_EDGES + 1) * 4);
    int* curN    = (int*)alloc((size_t)N_NODES * 4);
    int* curE    = (int*)alloc((size_t)M_EDGES * 4);
    int* bsums   = (int*)alloc((size_t)NTILES * 4);
    int* listN   = (int*)alloc((size_t)NNZF * 4);      // edges grouped by node
    int* listE   = (int*)alloc((size_t)NNZF * 4);      // nodes grouped by edge
    float* y     = (float*)alloc((size_t)M_EDGES * F_IN * 4);   // [M,128]
    float* z     = (float*)alloc((size_t)N_NODES * F_IN * 4);   // [N,128]; reused for hp
    float* h     = (float*)alloc((size_t)N_NODES * HID * 4);    // [N,256]

    // only the counters need zeroing; every other buffer is fully overwritten
    hipMemsetAsync(cntN, 0, (size_t)(N_NODES + M_EDGES) * 4, stream);

    hist_deg<<<(NNZF + 255) / 256, 256, 0, stream>>>(nidx, eidx, cntN, cntE, NNZF);
    scan_sums<<<NTILES, 256, 0, stream>>>(cntN, bsums);
    scan_write<<<NTILES, 256, 0, stream>>>(cntN, bsums,
                                           startN, curN, Dinv,
                                           startE, curE, Binv);
    fill_csr<<<(NNZF + 255) / 256, 256, 0, stream>>>(nidx, eidx, curN, curE,
                                                     listN, listE, NNZF);

    // layer 1 propagation (feature width 128, pre-GEMM)
    gather_rows<true, false><<<(M_EDGES + 3) / 4, 256, 0, stream>>>(
        x, startE, listE, Binv, nullptr, y, M_EDGES);          // y = Binv .* (S^T x)
    gather_rows<false, false><<<(N_NODES + 3) / 4, 256, 0, stream>>>(
        y, startN, listN, nullptr, nullptr, z, N_NODES);       // z = S y

    // h = elu( (Dinv .* z) @ W1 + b1 )   [N,256]
    dim3 g1((N_NODES + 63) / 64, HID / 64);
    gemm_tiled<true, true, true><<<g1, 256, 0, stream>>>(z, W1, b1, Dinv, h, N_NODES, F_IN, HID);

    // hp = h @ W2  [N,128]  (into z)
    dim3 g2((N_NODES + 63) / 64, F_OUT / 64);
    gemm_tiled<false, false, false><<<g2, 256, 0, stream>>>(h, W2, nullptr, nullptr, z, N_NODES, HID, F_OUT);

    // e = Binv .* (S^T hp)  -> output slot
    gather_rows<true, false><<<(M_EDGES + 3) / 4, 256, 0, stream>>>(
        z, startE, listE, Binv, nullptr, e_out, M_EDGES);
    // out = Dinv .* (S e) + b2
    gather_rows<true, true><<<(N_NODES + 3) / 4, 256, 0, stream>>>(
        e_out, startN, listN, Dinv, b2, out, N_NODES);
}

// Round 6
// 479.399 us; speedup vs baseline: 1.5004x; 1.1089x over previous
//
#include <hip/hip_runtime.h>
#include <stdint.h>

#define N_NODES 50000
#define M_EDGES 25000
#define NNZF    800000
#define F_IN    128
#define HID     256
#define F_OUT   128

#define NB_N 49   // ceil(50000/1024)
#define NB_E 25   // ceil(25000/1024)
#define NTILES (NB_N + NB_E)

// ---------------- histogram (int counts) ----------------
__global__ void hist_deg(const int* __restrict__ nidx, const int* __restrict__ eidx,
                         int* __restrict__ cntN, int* __restrict__ cntE, int nnz) {
    int i = blockIdx.x * blockDim.x + threadIdx.x;
    if (i < nnz) {
        atomicAdd(cntN + nidx[i], 1);
        atomicAdd(cntE + eidx[i], 1);
    }
}

// ---------------- hierarchical scan, phase A: per-1024-tile sums ----------------
__global__ __launch_bounds__(256) void scan_sums(const int* __restrict__ cnt,
                                                 int* __restrict__ bsums) {
    int b = blockIdx.x;
    int tile, n; const int* base;
    if (b < NB_N) { base = cnt;           n = N_NODES; tile = b; }
    else          { base = cnt + N_NODES; n = M_EDGES; tile = b - NB_N; }
    int i0 = tile * 1024 + threadIdx.x * 4;
    int s = 0;
    if (i0 < n) {                     // n % 4 == 0 so int4 never straddles
        int4 v = *reinterpret_cast<const int4*>(base + i0);
        s = v.x + v.y + v.z + v.w;
    }
    for (int off = 32; off > 0; off >>= 1) s += __shfl_down(s, off, 64);
    __shared__ int ws[4];
    int wid = threadIdx.x >> 6, lane = threadIdx.x & 63;
    if (lane == 0) ws[wid] = s;
    __syncthreads();
    if (threadIdx.x == 0) bsums[b] = ws[0] + ws[1] + ws[2] + ws[3];
}

// ---------------- phase B: per-tile scan + write starts/cur/inv (coalesced) ----------------
__global__ __launch_bounds__(256) void scan_write(
    const int* __restrict__ cnt, const int* __restrict__ bsums,
    int* __restrict__ startN, int* __restrict__ curN, float* __restrict__ invN,
    int* __restrict__ startE, int* __restrict__ curE, float* __restrict__ invE) {
    int b = blockIdx.x;
    int tile, n, lo; const int* base; int* starts; int* cur; float* inv;
    if (b < NB_N) { base = cnt;           n = N_NODES; tile = b;        starts = startN; cur = curN; inv = invN; lo = 0; }
    else          { base = cnt + N_NODES; n = M_EDGES; tile = b - NB_N; starts = startE; cur = curE; inv = invE; lo = NB_N; }
    int tid = threadIdx.x;
    int wid = tid >> 6, lane = tid & 63;

    // block offset = sum of this region's preceding tile sums
    __shared__ int red[4];
    int partial = 0;
    for (int i = lo + tid; i < b; i += 256) partial += bsums[i];
    for (int off = 32; off > 0; off >>= 1) partial += __shfl_down(partial, off, 64);
    if (lane == 0) red[wid] = partial;
    __syncthreads();
    int blockoff = red[0] + red[1] + red[2] + red[3];

    int i0 = tile * 1024 + tid * 4;
    int4 v = make_int4(0, 0, 0, 0);
    if (i0 < n) v = *reinterpret_cast<const int4*>(base + i0);
    int tsum = v.x + v.y + v.z + v.w;

    // wave inclusive scan of thread sums
    int x = tsum;
    for (int d = 1; d < 64; d <<= 1) {
        int y = __shfl_up(x, d, 64);
        if (lane >= d) x += y;
    }
    int wexcl = x - tsum;
    __shared__ int wsum[4];
    if (lane == 63) wsum[wid] = x;
    __syncthreads();
    int woff = 0;
    for (int w = 0; w < wid; ++w) woff += wsum[w];
    int excl = blockoff + woff + wexcl;

    if (i0 < n) {
        int4 st;
        st.x = excl;
        st.y = st.x + v.x;
        st.z = st.y + v.y;
        st.w = st.z + v.z;
        *reinterpret_cast<int4*>(starts + i0) = st;
        *reinterpret_cast<int4*>(cur + i0) = st;
        float4 iv;
        iv.x = (v.x > 0) ? 1.0f / (float)v.x : 0.0f;
        iv.y = (v.y > 0) ? 1.0f / (float)v.y : 0.0f;
        iv.z = (v.z > 0) ? 1.0f / (float)v.z : 0.0f;
        iv.w = (v.w > 0) ? 1.0f / (float)v.w : 0.0f;
        *reinterpret_cast<float4*>(inv + i0) = iv;
    }
    if (b == 0 && tid == 0) { startN[N_NODES] = NNZF; startE[M_EDGES] = NNZF; }
}

// ---------------- CSR fill, XCD-binned ----------------
// pass p = blockIdx & 7 (round-robin XCD mapping). Pass p writes only CSR rows
// whose id-bucket is p, so each XCD's L2 sees one contiguous ~400KB dest window
// and scattered 4B writes can accumulate full 64B lines before eviction.
__global__ __launch_bounds__(256) void fill_csr_binned(
    const int* __restrict__ nidx, const int* __restrict__ eidx,
    int* __restrict__ curN, int* __restrict__ curE,
    int* __restrict__ listN, int* __restrict__ listE, int nnz) {
    int p = blockIdx.x & 7;
    int blk = blockIdx.x >> 3;
    int nblk = gridDim.x >> 3;
    int stride = nblk * blockDim.x;
    for (int i = blk * blockDim.x + threadIdx.x; i < nnz; i += stride) {
        int nd = nidx[i], ed = eidx[i];
        if (ed / 3125 == p)             // M_EDGES/8 = 3125
            listE[atomicAdd(curE + ed, 1)] = nd;
        if (nd / 6250 == p)             // N_NODES/8 = 6250
            listN[atomicAdd(curN + nd, 1)] = ed;
    }
}

// ---------------- gather segment-sum of 128-wide rows ----------------
template<bool SCALE_DST, bool ADD_BIAS>
__global__ __launch_bounds__(256) void gather_rows(
    const float* __restrict__ src, const int* __restrict__ starts,
    const int* __restrict__ list, const float* __restrict__ dstscale,
    const float* __restrict__ bias, float* __restrict__ dst, int rows) {
    int row = blockIdx.x * 4 + (threadIdx.x >> 6);
    if (row >= rows) return;
    int lane = threadIdx.x & 63;
    const float* sp = src + lane * 2;
    int s0 = starts[row], s1 = starts[row + 1];
    float a0x = 0.f, a0y = 0.f, a1x = 0.f, a1y = 0.f;
    float a2x = 0.f, a2y = 0.f, a3x = 0.f, a3y = 0.f;
    int j = s0;
    for (; j + 4 <= s1; j += 4) {
        int i0 = list[j + 0], i1 = list[j + 1], i2 = list[j + 2], i3 = list[j + 3];
        float2 v0 = *reinterpret_cast<const float2*>(sp + (int64_t)i0 * 128);
        float2 v1 = *reinterpret_cast<const float2*>(sp + (int64_t)i1 * 128);
        float2 v2 = *reinterpret_cast<const float2*>(sp + (int64_t)i2 * 128);
        float2 v3 = *reinterpret_cast<const float2*>(sp + (int64_t)i3 * 128);
        a0x += v0.x; a0y += v0.y;
        a1x += v1.x; a1y += v1.y;
        a2x += v2.x; a2y += v2.y;
        a3x += v3.x; a3y += v3.y;
    }
    for (; j < s1; ++j) {
        int i0 = list[j];
        float2 v0 = *reinterpret_cast<const float2*>(sp + (int64_t)i0 * 128);
        a0x += v0.x; a0y += v0.y;
    }
    float ax = (a0x + a1x) + (a2x + a3x);
    float ay = (a0y + a1y) + (a2y + a3y);
    if (SCALE_DST) { float sc = dstscale[row]; ax *= sc; ay *= sc; }
    if (ADD_BIAS)  { ax += bias[lane * 2]; ay += bias[lane * 2 + 1]; }
    float2 o; o.x = ax; o.y = ay;
    *reinterpret_cast<float2*>(dst + (int64_t)row * 128 + lane * 2) = o;
}

// ---------------- tiled fp32 GEMM, k-major A tile + ds_read_b128 fragments ----------------
template<bool SCALE_A, bool ELU, bool HAS_BIAS>
__global__ __launch_bounds__(256) void gemm_tiled(
    const float* __restrict__ A, const float* __restrict__ B,
    const float* __restrict__ bias, const float* __restrict__ rowscale,
    float* __restrict__ C, int Mr, int K, int Nc) {
    __shared__ float Ast[16][68];   // k-major A tile, padded (68*4B = 16B-aligned rows)
    __shared__ float Bs[16][68];
    int tid = threadIdx.x;
    int tx = tid & 15, ty = tid >> 4;
    int rowBase = blockIdx.x * 64;
    int colBase = blockIdx.y * 64;

    int lr = tid >> 2, lc = (tid & 3) << 2;      // A load: row lr, k-offset lc..lc+3
    int br = tid >> 4, bc = (tid & 15) << 2;     // B load: k-row br, col bc..bc+3

    float c[4][4] = {};

    for (int k0 = 0; k0 < K; k0 += 16) {
        int ar = rowBase + lr;
        float4 av = make_float4(0.f, 0.f, 0.f, 0.f);
        if (ar < Mr) {
            av = *reinterpret_cast<const float4*>(A + (int64_t)ar * K + k0 + lc);
            if (SCALE_A) {
                float sc = rowscale[ar];
                av.x *= sc; av.y *= sc; av.z *= sc; av.w *= sc;
            }
        }
        Ast[lc + 0][lr] = av.x;
        Ast[lc + 1][lr] = av.y;
        Ast[lc + 2][lr] = av.z;
        Ast[lc + 3][lr] = av.w;

        float4 bv = *reinterpret_cast<const float4*>(B + (int64_t)(k0 + br) * Nc + colBase + bc);
        *reinterpret_cast<float4*>(&Bs[br][bc]) = bv;

        __syncthreads();
        #pragma unroll
        for (int kk = 0; kk < 16; ++kk) {
            float4 a4 = *reinterpret_cast<const float4*>(&Ast[kk][ty * 4]);
            float4 b4 = *reinterpret_cast<const float4*>(&Bs[kk][tx * 4]);
            c[0][0] += a4.x * b4.x;  c[0][1] += a4.x * b4.y;  c[0][2] += a4.x * b4.z;  c[0][3] += a4.x * b4.w;
            c[1][0] += a4.y * b4.x;  c[1][1] += a4.y * b4.y;  c[1][2] += a4.y * b4.z;  c[1][3] += a4.y * b4.w;
            c[2][0] += a4.z * b4.x;  c[2][1] += a4.z * b4.y;  c[2][2] += a4.z * b4.z;  c[2][3] += a4.z * b4.w;
            c[3][0] += a4.w * b4.x;  c[3][1] += a4.w * b4.y;  c[3][2] += a4.w * b4.z;  c[3][3] += a4.w * b4.w;
        }
        __syncthreads();
    }

    #pragma unroll
    for (int i = 0; i < 4; ++i) {
        int r = rowBase + ty * 4 + i;
        if (r >= Mr) continue;
        float4 o;
        float* cc = c[i];
        o.x = cc[0]; o.y = cc[1]; o.z = cc[2]; o.w = cc[3];
        if (HAS_BIAS) {
            float4 bv = *reinterpret_cast<const float4*>(bias + colBase + tx * 4);
            o.x += bv.x; o.y += bv.y; o.z += bv.z; o.w += bv.w;
        }
        if (ELU) {
            o.x = (o.x > 0.f) ? o.x : expm1f(o.x);
            o.y = (o.y > 0.f) ? o.y : expm1f(o.y);
            o.z = (o.z > 0.f) ? o.z : expm1f(o.z);
            o.w = (o.w > 0.f) ? o.w : expm1f(o.w);
        }
        *reinterpret_cast<float4*>(C + (int64_t)r * Nc + colBase + tx * 4) = o;
    }
}

// ---------------- launch ----------------
extern "C" void kernel_launch(void* const* d_in, const int* in_sizes, int n_in,
                              void* d_out, int out_size, void* d_ws, size_t ws_size,
                              hipStream_t stream) {
    const float* x   = (const float*)d_in[0];
    const float* W1  = (const float*)d_in[1];
    const float* b1  = (const float*)d_in[2];
    const float* W2  = (const float*)d_in[3];
    const float* b2  = (const float*)d_in[4];
    const int*   nidx = (const int*)d_in[5];
    const int*   eidx = (const int*)d_in[6];

    float* out   = (float*)d_out;                      // [N, 128]
    float* e_out = out + (size_t)N_NODES * F_OUT;      // [M, 128]

    char* ws = (char*)d_ws;
    size_t off = 0;
    auto alloc = [&](size_t bytes) -> void* {
        void* p = ws + off;
        off += (bytes + 511) & ~(size_t)511;
        return p;
    };
    int* cntN    = (int*)alloc((size_t)(N_NODES + M_EDGES) * 4);   // contiguous: cntN | cntE
    int* cntE    = cntN + N_NODES;
    float* Dinv  = (float*)alloc((size_t)N_NODES * 4);
    float* Binv  = (float*)alloc((size_t)M_EDGES * 4);
    int* startN  = (int*)alloc((size_t)(N_NODES + 1) * 4);
    int* startE  = (int*)alloc((size_t)(M_EDGES + 1) * 4);
    int* curN    = (int*)alloc((size_t)N_NODES * 4);
    int* curE    = (int*)alloc((size_t)M_EDGES * 4);
    int* bsums   = (int*)alloc((size_t)NTILES * 4);
    int* listN   = (int*)alloc((size_t)NNZF * 4);      // edges grouped by node
    int* listE   = (int*)alloc((size_t)NNZF * 4);      // nodes grouped by edge
    float* y     = (float*)alloc((size_t)M_EDGES * F_IN * 4);   // [M,128]
    float* z     = (float*)alloc((size_t)N_NODES * F_IN * 4);   // [N,128]; reused for hp
    float* h     = (float*)alloc((size_t)N_NODES * HID * 4);    // [N,256]

    // only the counters need zeroing; every other buffer is fully overwritten
    hipMemsetAsync(cntN, 0, (size_t)(N_NODES + M_EDGES) * 4, stream);

    hist_deg<<<(NNZF + 255) / 256, 256, 0, stream>>>(nidx, eidx, cntN, cntE, NNZF);
    scan_sums<<<NTILES, 256, 0, stream>>>(cntN, bsums);
    scan_write<<<NTILES, 256, 0, stream>>>(cntN, bsums,
                                           startN, curN, Dinv,
                                           startE, curE, Binv);
    // 8 pass-groups (one per XCD via blockIdx%8), each covering all 800K entries
    {
        int nblk_per_pass = (NNZF + 255) / 256;        // 3125
        fill_csr_binned<<<nblk_per_pass * 8, 256, 0, stream>>>(
            nidx, eidx, curN, curE, listN, listE, NNZF);
    }

    // layer 1 propagation (feature width 128, pre-GEMM)
    gather_rows<true, false><<<(M_EDGES + 3) / 4, 256, 0, stream>>>(
        x, startE, listE, Binv, nullptr, y, M_EDGES);          // y = Binv .* (S^T x)
    gather_rows<false, false><<<(N_NODES + 3) / 4, 256, 0, stream>>>(
        y, startN, listN, nullptr, nullptr, z, N_NODES);       // z = S y

    // h = elu( (Dinv .* z) @ W1 + b1 )   [N,256]
    dim3 g1((N_NODES + 63) / 64, HID / 64);
    gemm_tiled<true, true, true><<<g1, 256, 0, stream>>>(z, W1, b1, Dinv, h, N_NODES, F_IN, HID);

    // hp = h @ W2  [N,128]  (into z)
    dim3 g2((N_NODES + 63) / 64, F_OUT / 64);
    gemm_tiled<false, false, false><<<g2, 256, 0, stream>>>(h, W2, nullptr, nullptr, z, N_NODES, HID, F_OUT);

    // e = Binv .* (S^T hp)  -> output slot
    gather_rows<true, false><<<(M_EDGES + 3) / 4, 256, 0, stream>>>(
        z, startE, listE, Binv, nullptr, e_out, M_EDGES);
    // out = Dinv .* (S e) + b2
    gather_rows<true, true><<<(N_NODES + 3) / 4, 256, 0, stream>>>(
        e_out, startN, listN, Dinv, b2, out, N_NODES);
}